// Round 4
// baseline (1662.659 us; speedup 1.0000x reference)
//
#include <hip/hip_runtime.h>

typedef unsigned int u32;
typedef unsigned short u16;

#define S_LEN 1024
#define NH 32
#define NKV 8
#define DW 64      // dwords per head row (128 bf16 = 64 u32)
#define KPAD 68    // padded LDS row stride in dwords (16B-aligned, conflict-free b128)
#define NEG_BIG (-1e30f)

typedef __bf16 bf16x8 __attribute__((ext_vector_type(8)));
typedef float f32x4 __attribute__((ext_vector_type(4)));

__device__ __forceinline__ u16 f2bf(float f) {
  u32 u = __builtin_bit_cast(u32, f);
  u += 0x7fffu + ((u >> 16) & 1u);   // RNE
  return (u16)(u >> 16);
}
__device__ __forceinline__ float bflo(u32 u) { return __builtin_bit_cast(float, u << 16); }
__device__ __forceinline__ float bfhi(u32 u) { return __builtin_bit_cast(float, u & 0xffff0000u); }

// ---------------------------------------------------------------------------
// C = A @ B^T.  A: (M,K) fp32 or bf16 row-major.  B: (N,K) fp32 row-major.
// C: (M,N) bf16 (BF16OUT) or fp32.  M,N multiples of 128, K multiple of 32.
// 128x128 block tile, 4 waves, each wave 64x64 (4x4 MFMA 16x16x32 bf16 tiles).
// Verified-pattern fragment layouts (m92/m97 ladder):
//   A-frag: A[m=lane&15][k=quad*8+j];  B-frag from B^T: B[n=lane&15][k=quad*8+j]
//   C/D:    row = quad*4+reg, col = lane&15
// ---------------------------------------------------------------------------
template <bool A_BF16, bool BF16OUT>
__launch_bounds__(256)
__global__ void gemm_bt(const void* __restrict__ Av, const float* __restrict__ B,
                        void* __restrict__ Cv, int M, int N, int K) {
  __shared__ u32 As[128 * 16];   // 128 rows x 32 bf16
  __shared__ u32 Bs[128 * 16];
  const int tid = threadIdx.x;
  const int lane = tid & 63, w = tid >> 6;
  const int wr = w >> 1, wc = w & 1;
  const int col = lane & 15, quad = lane >> 4;
  const int m0 = blockIdx.y * 128, n0 = blockIdx.x * 128;

  f32x4 acc[4][4] = {};

  for (int k0 = 0; k0 < K; k0 += 32) {
    // ---- stage A tile (128x32) into As as bf16 ----
    if constexpr (A_BF16) {
      const u16* A = (const u16*)Av;
#pragma unroll
      for (int i = 0; i < 2; ++i) {
        int f = i * 256 + tid;          // 512 uint4 per tile
        int row = f >> 2, c4 = f & 3;
        *(uint4*)&As[row * 16 + c4 * 4] =
            *((const uint4*)(A + (size_t)(m0 + row) * K + k0) + c4);
      }
    } else {
      const float* A = (const float*)Av;
#pragma unroll
      for (int i = 0; i < 4; ++i) {
        int f = i * 256 + tid;          // 1024 float4 per tile
        int row = f >> 3, c4 = f & 7;
        float4 a = *((const float4*)(A + (size_t)(m0 + row) * K + k0) + c4);
        u32 a0 = (u32)f2bf(a.x) | ((u32)f2bf(a.y) << 16);
        u32 a1 = (u32)f2bf(a.z) | ((u32)f2bf(a.w) << 16);
        *(uint2*)&As[row * 16 + c4 * 2] = make_uint2(a0, a1);
      }
    }
    // ---- stage B tile (128x32) fp32 -> bf16 ----
#pragma unroll
    for (int i = 0; i < 4; ++i) {
      int f = i * 256 + tid;
      int row = f >> 3, c4 = f & 7;
      float4 b = *((const float4*)(B + (size_t)(n0 + row) * K + k0) + c4);
      u32 b0 = (u32)f2bf(b.x) | ((u32)f2bf(b.y) << 16);
      u32 b1 = (u32)f2bf(b.z) | ((u32)f2bf(b.w) << 16);
      *(uint2*)&Bs[row * 16 + c4 * 2] = make_uint2(b0, b1);
    }
    __syncthreads();
    bf16x8 af[4], bfr[4];
#pragma unroll
    for (int i = 0; i < 4; ++i) {
      int m = wr * 64 + i * 16 + col;
      af[i] = *reinterpret_cast<const bf16x8*>(&As[m * 16 + quad * 4]);
      int n = wc * 64 + i * 16 + col;
      bfr[i] = *reinterpret_cast<const bf16x8*>(&Bs[n * 16 + quad * 4]);
    }
#pragma unroll
    for (int i = 0; i < 4; ++i)
#pragma unroll
      for (int j = 0; j < 4; ++j)
        acc[i][j] = __builtin_amdgcn_mfma_f32_16x16x32_bf16(af[i], bfr[j], acc[i][j], 0, 0, 0);
    __syncthreads();
  }

#pragma unroll
  for (int i = 0; i < 4; ++i)
#pragma unroll
    for (int j = 0; j < 4; ++j)
#pragma unroll
      for (int r = 0; r < 4; ++r) {
        int row = m0 + wr * 64 + i * 16 + quad * 4 + r;   // C/D: row = quad*4+reg
        int cc  = n0 + wc * 64 + j * 16 + col;            //      col = lane&15
        float v = acc[i][j][r];
        if constexpr (BF16OUT) ((u16*)Cv)[(size_t)row * N + cc] = f2bf(v);
        else                   ((float*)Cv)[(size_t)row * N + cc] = v;
      }
}

// ---------------------------------------------------------------------------
// In-place RoPE on bf16 (B,S,heads,64 pairs). pair p: (x0,x1) packed in u32.
// ---------------------------------------------------------------------------
__launch_bounds__(256)
__global__ void rope_kernel(u32* __restrict__ buf, int heads, int npairs) {
  int p = blockIdx.x * 256 + threadIdx.x;
  if (p >= npairs) return;
  int d2 = p & 63;
  int s = (p / (64 * heads)) % S_LEN;
  // inv_freq = 10000^(-d2/64) = exp(-d2 * ln(10000)/64)
  float ang = (float)s * expf((float)d2 * -0.14391156831212787f);
  float sn, cs;
  sincosf(ang, &sn, &cs);   // accurate range reduction (ang up to ~1023 rad)
  u32 u = buf[p];
  float x0 = bflo(u), x1 = bfhi(u);
  float y0 = x0 * cs - x1 * sn;
  float y1 = x0 * sn + x1 * cs;
  buf[p] = (u32)f2bf(y0) | ((u32)f2bf(y1) << 16);
}

// ---------------------------------------------------------------------------
// Causal GQA attention, online softmax (finite -1e30 sentinels).
// Block = 4 waves = 4 consecutive q rows of one (b,h). 64-key LDS tiles:
// Ks[key][dimpair] (pad 68), V transposed Vt[dimpair][key].
// Dot phase: lane=key. PV phase: lane=dim-pair. O fp32, 2 dims/lane.
// FIX (r4): commit running max (m_i = m_new) — was missing, so alpha==0 every
// tile and each query attended only its last tile (absmax 7.05 in r1/r2).
// ---------------------------------------------------------------------------
__launch_bounds__(256)
__global__ void attn_kernel(const u32* __restrict__ Qb, const u32* __restrict__ Kb,
                            const u32* __restrict__ Vb, u32* __restrict__ Ob) {
  __shared__ u32 Ks[64 * KPAD];
  __shared__ u32 Vt[64 * KPAD];
  __shared__ float Ps[4][64];
  __shared__ u32 Qs[4][64];
  const int tid = threadIdx.x, lane = tid & 63, w = tid >> 6;
  const int bx = blockIdx.x, h = blockIdx.y, b = blockIdx.z;
  const int kh = h >> 2;           // N_REP = 4
  const int q = bx * 4 + w;

  Qs[w][lane] = Qb[((size_t)((b * S_LEN + q) * NH + h)) * DW + lane];

  float m_i = NEG_BIG, l_i = 0.f, o0 = 0.f, o1 = 0.f;
  const int ntiles = (bx * 4 + 4 + 63) >> 6;

  for (int tt = 0; tt < ntiles; ++tt) {
    const int t0 = tt * 64;
    __syncthreads();
#pragma unroll
    for (int i = 0; i < 4; ++i) {
      int f = i * 256 + tid;
      int row = f >> 4, c4 = f & 15;
      size_t base = ((size_t)(b * S_LEN + t0 + row) * NKV + kh) * DW;
      uint4 kk = *((const uint4*)(Kb + base) + c4);
      uint4 vv = *((const uint4*)(Vb + base) + c4);
      u32* kd = &Ks[row * KPAD + c4 * 4];
      kd[0] = kk.x; kd[1] = kk.y; kd[2] = kk.z; kd[3] = kk.w;
      Vt[(c4 * 4 + 0) * KPAD + row] = vv.x;
      Vt[(c4 * 4 + 1) * KPAD + row] = vv.y;
      Vt[(c4 * 4 + 2) * KPAD + row] = vv.z;
      Vt[(c4 * 4 + 3) * KPAD + row] = vv.w;
    }
    __syncthreads();

    // score for key (t0+lane)
    float s = 0.f;
#pragma unroll
    for (int i = 0; i < 16; ++i) {
      uint4 kk = *(const uint4*)&Ks[lane * KPAD + i * 4];
      uint4 qq = *(const uint4*)&Qs[w][i * 4];       // broadcast
      s += bflo(qq.x) * bflo(kk.x) + bfhi(qq.x) * bfhi(kk.x);
      s += bflo(qq.y) * bflo(kk.y) + bfhi(qq.y) * bfhi(kk.y);
      s += bflo(qq.z) * bflo(kk.z) + bfhi(qq.z) * bfhi(kk.z);
      s += bflo(qq.w) * bflo(kk.w) + bfhi(qq.w) * bfhi(kk.w);
    }
    s *= 0.08838834764831845f;     // 1/sqrt(128)
    int tg = t0 + lane;
    s = (tg <= q) ? s : NEG_BIG;

    float mt = s;
#pragma unroll
    for (int off = 32; off; off >>= 1) mt = fmaxf(mt, __shfl_xor(mt, off));
    float m_new = fmaxf(m_i, mt);            // finite from tile 0 (key 0 valid)
    float alpha = __expf(m_i - m_new);
    float p = __expf(s - m_new);             // masked lanes: exp(~-1e30) = 0
    float ps = p;
#pragma unroll
    for (int off = 32; off; off >>= 1) ps += __shfl_xor(ps, off);
    l_i = l_i * alpha + ps;
    o0 *= alpha; o1 *= alpha;
    m_i = m_new;                              // <<< THE FIX
    Ps[w][lane] = p;                          // wave-private row; in-wave DS order

#pragma unroll
    for (int jb = 0; jb < 16; ++jb) {
      float4 pp = *(const float4*)&Ps[w][jb * 4];          // broadcast
      uint4 vv = *(const uint4*)&Vt[lane * KPAD + jb * 4]; // lane's 2 dims, 4 keys
      o0 += pp.x * bflo(vv.x); o1 += pp.x * bfhi(vv.x);
      o0 += pp.y * bflo(vv.y); o1 += pp.y * bfhi(vv.y);
      o0 += pp.z * bflo(vv.z); o1 += pp.z * bfhi(vv.z);
      o0 += pp.w * bflo(vv.w); o1 += pp.w * bfhi(vv.w);
    }
  }

  float invl = 1.0f / l_i;
  Ob[((size_t)((b * S_LEN + q) * NH + h)) * DW + lane] =
      (u32)f2bf(o0 * invl) | ((u32)f2bf(o1 * invl) << 16);
}

// ---------------------------------------------------------------------------
// fp32 inputs & fp32 output (reference dtypes; confirmed by r1/r2 vs r3
// evidence). Internals bf16.
// Plan: Qb bf16 -> d_out (scratch; final fp32 GEMM overwrites all 32 MiB,
//       reading only ws).  ws: [0,4M) Kb | [4M,8M) Vb | [8M,24M) Ob bf16.
// ---------------------------------------------------------------------------
extern "C" void kernel_launch(void* const* d_in, const int* in_sizes, int n_in,
                              void* d_out, int out_size, void* d_ws, size_t ws_size,
                              hipStream_t stream) {
  const float* hs = (const float*)d_in[0];
  const float* Wq = (const float*)d_in[1];
  const float* Wk = (const float*)d_in[2];
  const float* Wv = (const float*)d_in[3];
  const float* Wo = (const float*)d_in[4];

  u16* Qb = (u16*)d_out;
  char* ws = (char*)d_ws;
  u16* Kb = (u16*)ws;
  u16* Vb = (u16*)(ws + (4u << 20));
  u16* Ob = (u16*)(ws + (8u << 20));

  dim3 blk(256);
  // QKV projections (fp32 in, bf16 out)
  gemm_bt<false, true><<<dim3(32, 16), blk, 0, stream>>>(hs, Wq, (void*)Qb, 2048, 4096, 4096);
  gemm_bt<false, true><<<dim3(8, 16), blk, 0, stream>>>(hs, Wk, (void*)Kb, 2048, 1024, 4096);
  gemm_bt<false, true><<<dim3(8, 16), blk, 0, stream>>>(hs, Wv, (void*)Vb, 2048, 1024, 4096);
  // RoPE in-place on Q and K
  rope_kernel<<<16384, blk, 0, stream>>>((u32*)Qb, NH, 2048 * NH * 64);
  rope_kernel<<<4096, blk, 0, stream>>>((u32*)Kb, NKV, 2048 * NKV * 64);
  // causal GQA attention -> Ob bf16 (ws)
  attn_kernel<<<dim3(S_LEN / 4, NH, 2), blk, 0, stream>>>((const u32*)Qb, (const u32*)Kb,
                                                          (const u32*)Vb, (u32*)Ob);
  // output projection: bf16 A (Ob) x fp32 B (Wo) -> fp32 C overwrites d_out
  gemm_bt<true, false><<<dim3(32, 16), blk, 0, stream>>>((const void*)Ob, Wo, d_out,
                                                         2048, 4096, 4096);
}